// Round 1
// baseline (363.834 us; speedup 1.0000x reference)
//
#include <hip/hip_runtime.h>
#include <math.h>

#define HID 4096
#define R_TOTAL 16384

// ---------------------------------------------------------------------------
// Phase 1: y = x@w1 + b1 -> LN(g1,beta1) -> SiLU -> @w2 + b2 = wave_input
// Also accumulates column sums of wave_input into gacc (for the global mean).
// Block: 256 threads, 64 rows. Grid: 256.
// GEMM: split-K x2, per-thread 4x4 tile, LDS chunk HC=64.
// ---------------------------------------------------------------------------
__global__ __launch_bounds__(256) void wn_phase1(
    const float* __restrict__ x, const float* __restrict__ w1,
    const float* __restrict__ b1, const float* __restrict__ g1,
    const float* __restrict__ beta1, const float* __restrict__ w2,
    const float* __restrict__ b2, float* __restrict__ wi_out,
    float* __restrict__ gacc)
{
  __shared__ __align__(16) float lds[7168];
  float* xT  = lds;            // [64 hh][68]  xT[hh*68 + row] = x[r0+row][h0+hh]
  float* wl  = lds + 4352;     // [64 hh][36]  wl[hh*36 + c]   = w1[h0+hh][c]
  float* w2l = lds + 6656;     // [32][16]
  const int t  = threadIdx.x;
  const int r0 = blockIdx.x * 64;

  if (t < 128) *(float4*)&w2l[t*4] = *(const float4*)&w2[t*4];

  const int ks   = t >> 7;     // split-K half
  const int u    = t & 127;
  const int trow = u >> 3;     // 0..15 -> rows trow*4..+3
  const int tcol = u & 7;      // 0..7  -> cols tcol*4..+3
  float acc[4][4] = {};

  for (int h0 = 0; h0 < HID; h0 += 64) {
    __syncthreads();
    // stage x chunk (transposed into [hh][row])
    #pragma unroll
    for (int k = 0; k < 4; ++k) {
      const int idx = t + k*256;
      const int row = idx >> 4, hh4 = idx & 15;
      const float4 v = *(const float4*)&x[(size_t)(r0+row)*HID + h0 + hh4*4];
      xT[(hh4*4+0)*68 + row] = v.x;
      xT[(hh4*4+1)*68 + row] = v.y;
      xT[(hh4*4+2)*68 + row] = v.z;
      xT[(hh4*4+3)*68 + row] = v.w;
    }
    // stage w1 chunk
    #pragma unroll
    for (int k = 0; k < 2; ++k) {
      const int idx = t + k*256;
      const int hh = idx >> 3, c4 = idx & 7;
      *(float4*)&wl[hh*36 + c4*4] = *(const float4*)&w1[(size_t)(h0+hh)*32 + c4*4];
    }
    __syncthreads();
    #pragma unroll
    for (int s = 0; s < 32; ++s) {
      const int hh = ks*32 + s;
      const float4 xv = *(const float4*)&xT[hh*68 + trow*4];
      const float4 wv = *(const float4*)&wl[hh*36 + tcol*4];
      const float xa[4] = {xv.x, xv.y, xv.z, xv.w};
      const float wa[4] = {wv.x, wv.y, wv.z, wv.w};
      #pragma unroll
      for (int i = 0; i < 4; ++i)
        #pragma unroll
        for (int j = 0; j < 4; ++j)
          acc[i][j] = fmaf(xa[i], wa[j], acc[i][j]);
    }
  }
  __syncthreads();
  // combine split-K halves via LDS scratch (reuse xT region)
  if (ks) {
    float* sc = &xT[u*16];
    #pragma unroll
    for (int i = 0; i < 4; ++i)
      #pragma unroll
      for (int j = 0; j < 4; ++j) sc[i*4+j] = acc[i][j];
  }
  __syncthreads();
  if (!ks) {
    const float* sc = &xT[u*16];
    #pragma unroll
    for (int i = 0; i < 4; ++i)
      #pragma unroll
      for (int j = 0; j < 4; ++j)
        wl[(trow*4+i)*33 + tcol*4+j] = acc[i][j] + sc[i*4+j];   // y_lds [64][33]
  }
  __syncthreads();
  // per-row epilogue: +b1, LN, SiLU, @w2+b2 -> wave_input
  if (t < 64) {
    float v[32];
    float mu = 0.f;
    #pragma unroll
    for (int d = 0; d < 32; ++d) { v[d] = wl[t*33+d] + b1[d]; mu += v[d]; }
    mu *= (1.f/32.f);
    float var = 0.f;
    #pragma unroll
    for (int d = 0; d < 32; ++d) { const float c = v[d]-mu; var += c*c; }
    const float rs = rsqrtf(var*(1.f/32.f) + 1e-5f);
    float wiv[16];
    #pragma unroll
    for (int w = 0; w < 16; ++w) wiv[w] = b2[w];
    #pragma unroll
    for (int d = 0; d < 32; ++d) {
      const float hn = (v[d]-mu)*rs*g1[d] + beta1[d];
      const float sl = hn / (1.f + __expf(-hn));
      const float* wr = &w2l[d*16];
      #pragma unroll
      for (int w = 0; w < 16; ++w) wiv[w] = fmaf(sl, wr[w], wiv[w]);
    }
    float* dst = &wi_out[(size_t)(r0+t)*16];
    #pragma unroll
    for (int g = 0; g < 4; ++g) {
      float4 o; o.x = wiv[g*4]; o.y = wiv[g*4+1]; o.z = wiv[g*4+2]; o.w = wiv[g*4+3];
      *(float4*)&dst[g*4] = o;
    }
    #pragma unroll
    for (int w = 0; w < 16; ++w) xT[t*17 + w] = wiv[w];   // reduce scratch [64][17]
  }
  __syncthreads();
  if (t < 16) {
    float s = 0.f;
    for (int r = 0; r < 64; ++r) s += xT[r*17 + t];
    atomicAdd(gacc + t, s);
  }
}

// ---------------------------------------------------------------------------
// Phase 2: coupled[16] and resonance_factor (scalar), from gacc sums.
// ---------------------------------------------------------------------------
__global__ void wn_phase2(const float* __restrict__ freq, const float* __restrict__ phases,
    const float* __restrict__ coupling, const float* __restrict__ damping,
    const float* __restrict__ tstep, const float* __restrict__ gacc,
    float* __restrict__ cpl)
{
  __shared__ float base[16];
  __shared__ float res[16];
  const int t = threadIdx.x;
  const float tt = tstep[0] + 0.1f;
  if (t < 16)
    base[t] = sinf(6.283185307179586f * freq[t] * tt + phases[t]) * expf(-damping[t]*tt);
  __syncthreads();
  if (t < 16) {
    float s = 0.f;
    for (int i = 0; i < 16; ++i) s += base[i] * coupling[i*16 + t];
    const float c = tanhf(s);
    cpl[t] = c;
    const float mw = c * (1.f + gacc[t] * (1.f/16384.f));
    res[t] = 0.1f * fabsf(mw);
  }
  __syncthreads();
  if (t == 0) {
    float s = 0.f;
    for (int w = 0; w < 16; ++w) s += res[w];
    const float m = s * (1.f/16.f);
    cpl[16] = 1.f / (1.f + expf(-m));
  }
}

// ---------------------------------------------------------------------------
// Phase 3: mod = coupled*(1+wi); o = SiLU(LN(mod@w3+b3)); out = x + rf*(o@w4+b4)
// Block: 256 threads, 64 rows. Grid: 256. w4 chunk [32][128] staged in LDS.
// ---------------------------------------------------------------------------
__global__ __launch_bounds__(256) void wn_phase3(
    const float* __restrict__ x, const float* __restrict__ wi_in,
    const float* __restrict__ w3, const float* __restrict__ b3,
    const float* __restrict__ g2, const float* __restrict__ beta2,
    const float* __restrict__ w4, const float* __restrict__ b4,
    const float* __restrict__ cpl, float* __restrict__ out)
{
  __shared__ __align__(16) float lds[6912];
  // o:   [0,2304)    [64][36]
  // w4l: [2304,6400) [32][128]
  // w3l: [6400,6912) [16][32]
  const int t  = threadIdx.x;
  const int r0 = blockIdx.x * 64;
  if (t < 128) *(float4*)&lds[6400 + t*4] = *(const float4*)&w3[t*4];
  const float rf = cpl[16];
  // --- step A: per-row o[32] ---
  {
    const int row = t >> 2, q = t & 3;      // 4 threads per row, 8 d's each
    const float* wip = &wi_in[(size_t)(r0+row)*16];
    float mod[16];
    #pragma unroll
    for (int g = 0; g < 4; ++g) {
      const float4 v = *(const float4*)&wip[g*4];
      mod[g*4+0] = cpl[g*4+0]*(1.f+v.x);
      mod[g*4+1] = cpl[g*4+1]*(1.f+v.y);
      mod[g*4+2] = cpl[g*4+2]*(1.f+v.z);
      mod[g*4+3] = cpl[g*4+3]*(1.f+v.w);
    }
    __syncthreads();   // w3l ready
    float p[8];
    #pragma unroll
    for (int dd = 0; dd < 8; ++dd) p[dd] = b3[q*8+dd];
    #pragma unroll
    for (int w = 0; w < 16; ++w) {
      const float m = mod[w];
      const float* wr = &lds[6400 + w*32 + q*8];
      #pragma unroll
      for (int dd = 0; dd < 8; ++dd) p[dd] = fmaf(m, wr[dd], p[dd]);
    }
    float s = 0.f;
    #pragma unroll
    for (int dd = 0; dd < 8; ++dd) s += p[dd];
    s += __shfl_xor(s, 1); s += __shfl_xor(s, 2);
    const float mu = s * (1.f/32.f);
    float vs = 0.f;
    #pragma unroll
    for (int dd = 0; dd < 8; ++dd) { const float c = p[dd]-mu; vs += c*c; }
    vs += __shfl_xor(vs, 1); vs += __shfl_xor(vs, 2);
    const float rs = rsqrtf(vs*(1.f/32.f) + 1e-5f);
    float o[8];
    #pragma unroll
    for (int dd = 0; dd < 8; ++dd) {
      const int d = q*8+dd;
      const float hn = (p[dd]-mu)*rs*g2[d] + beta2[d];
      o[dd] = hn / (1.f + __expf(-hn));
    }
    float4 o0; o0.x=o[0]; o0.y=o[1]; o0.z=o[2]; o0.w=o[3];
    float4 o1; o1.x=o[4]; o1.y=o[5]; o1.z=o[6]; o1.w=o[7];
    *(float4*)&lds[row*36 + q*8]     = o0;
    *(float4*)&lds[row*36 + q*8 + 4] = o1;
  }
  // --- step B: out = x + rf*(o@w4 + b4) ---
  const int trow = t >> 6, tcol = t & 63;   // trow constant per wave -> o broadcast
  for (int h0 = 0; h0 < HID; h0 += 128) {
    __syncthreads();
    #pragma unroll
    for (int k = 0; k < 4; ++k) {
      const int idx = t + k*256;
      const int d = idx >> 5, hc4 = idx & 31;
      *(float4*)&lds[2304 + d*128 + hc4*4] = *(const float4*)&w4[(size_t)d*HID + h0 + hc4*4];
    }
    __syncthreads();
    const float2 b4v = *(const float2*)&b4[h0 + tcol*2];
    #pragma unroll
    for (int rb = 0; rb < 4; ++rb) {
      const int rbase = rb*16 + trow*4;
      float a[4][2] = {};
      #pragma unroll
      for (int d4 = 0; d4 < 8; ++d4) {
        float oa[4][4];
        #pragma unroll
        for (int i = 0; i < 4; ++i) {
          const float4 ov = *(const float4*)&lds[(rbase+i)*36 + d4*4];
          oa[i][0]=ov.x; oa[i][1]=ov.y; oa[i][2]=ov.z; oa[i][3]=ov.w;
        }
        #pragma unroll
        for (int dd = 0; dd < 4; ++dd) {
          const float2 wv = *(const float2*)&lds[2304 + (d4*4+dd)*128 + tcol*2];
          #pragma unroll
          for (int i = 0; i < 4; ++i) {
            a[i][0] = fmaf(oa[i][dd], wv.x, a[i][0]);
            a[i][1] = fmaf(oa[i][dd], wv.y, a[i][1]);
          }
        }
      }
      #pragma unroll
      for (int i = 0; i < 4; ++i) {
        const size_t off = (size_t)(r0+rbase+i)*HID + h0 + tcol*2;
        const float2 xv = *(const float2*)&x[off];
        float2 o2;
        o2.x = fmaf(rf, a[i][0]+b4v.x, xv.x);
        o2.y = fmaf(rf, a[i][1]+b4v.y, xv.y);
        *(float2*)&out[off] = o2;
      }
    }
  }
}

extern "C" void kernel_launch(void* const* d_in, const int* in_sizes, int n_in,
                              void* d_out, int out_size, void* d_ws, size_t ws_size,
                              hipStream_t stream) {
  const float* x        = (const float*)d_in[0];
  const float* freq     = (const float*)d_in[1];
  const float* phases   = (const float*)d_in[2];
  const float* coupling = (const float*)d_in[3];
  const float* damping  = (const float*)d_in[4];
  const float* w1       = (const float*)d_in[5];
  const float* b1       = (const float*)d_in[6];
  const float* g1       = (const float*)d_in[7];
  const float* beta1    = (const float*)d_in[8];
  const float* w2       = (const float*)d_in[9];
  const float* b2       = (const float*)d_in[10];
  const float* w3       = (const float*)d_in[11];
  const float* b3       = (const float*)d_in[12];
  const float* g2       = (const float*)d_in[13];
  const float* beta2    = (const float*)d_in[14];
  const float* w4       = (const float*)d_in[15];
  const float* b4       = (const float*)d_in[16];
  const float* tstep    = (const float*)d_in[17];
  float* out = (float*)d_out;

  float* wsf  = (float*)d_ws;
  float* wi   = wsf;                          // [16384][16]
  float* gacc = wsf + (size_t)R_TOTAL*16;     // [16]
  float* cpl  = gacc + 16;                    // coupled[16] + rf at [16]

  hipMemsetAsync(gacc, 0, 16*sizeof(float), stream);
  hipLaunchKernelGGL(wn_phase1, dim3(256), dim3(256), 0, stream,
                     x, w1, b1, g1, beta1, w2, b2, wi, gacc);
  hipLaunchKernelGGL(wn_phase2, dim3(1), dim3(64), 0, stream,
                     freq, phases, coupling, damping, tstep, gacc, cpl);
  hipLaunchKernelGGL(wn_phase3, dim3(256), dim3(256), 0, stream,
                     x, wi, w3, b3, g2, beta2, w4, b4, cpl, out);
}

// Round 2
// 241.368 us; speedup vs baseline: 1.5074x; 1.5074x over previous
//
#include <hip/hip_runtime.h>
#include <math.h>

#define HID 4096
#define R_TOTAL 16384

// ---------------------------------------------------------------------------
// Phase 0: coupled[16] -> cpl[0..15]  (no dependency on x)
// ---------------------------------------------------------------------------
__global__ void wn_phase0(const float* __restrict__ freq, const float* __restrict__ phases,
    const float* __restrict__ coupling, const float* __restrict__ damping,
    const float* __restrict__ tstep, float* __restrict__ cpl)
{
  __shared__ float base[16];
  const int t = threadIdx.x;
  const float tt = tstep[0] + 0.1f;
  if (t < 16)
    base[t] = sinf(6.283185307179586f*freq[t]*tt + phases[t]) * expf(-damping[t]*tt);
  __syncthreads();
  if (t < 16) {
    float s = 0.f;
    #pragma unroll
    for (int i = 0; i < 16; ++i) s += base[i]*coupling[i*16+t];
    cpl[t] = tanhf(s);
  }
}

// ---------------------------------------------------------------------------
// Phase 1: y = x@w1+b1 -> LN -> SiLU -> @w2+b2 -> mod = cpl*(1+wi)
//          -> p = mod@w3+b3 -> LN -> SiLU -> o  (written to ws, [16384][32])
// Accumulates column sums of mod into gacc. 512 blocks x 512 thr, 32 rows/blk,
// split-K x8 (one K-slice per wave).
// ---------------------------------------------------------------------------
__global__ __launch_bounds__(512, 4) void wn_phase1(
    const float* __restrict__ x, const float* __restrict__ w1,
    const float* __restrict__ b1, const float* __restrict__ g1,
    const float* __restrict__ beta1, const float* __restrict__ w2,
    const float* __restrict__ b2, const float* __restrict__ w3,
    const float* __restrict__ b3, const float* __restrict__ g2,
    const float* __restrict__ beta2, const float* __restrict__ cpl,
    float* __restrict__ o_ws, float* __restrict__ gacc)
{
  __shared__ __align__(16) float lds[10816];
  float* xT   = lds;           // [64 hh][36]   (main loop)
  float* w1l  = lds + 2304;    // [64 hh][36]   (main loop)
  float* red  = lds;           // [8][1024]     (after loop; overlays xT/w1l)
  float* yl   = lds + 8192;    // [32][33]
  float* w2l  = lds + 9248;    // [32][16]
  float* w3l  = lds + 9760;    // [16][32]
  float* msum = lds + 10272;   // [32][17]
  const int t  = threadIdx.x;
  const int r0 = blockIdx.x * 32;

  if (t < 128) *(float4*)&w2l[t*4] = *(const float4*)&w2[t*4];
  else if (t < 256) { const int u2 = t-128; *(float4*)&w3l[u2*4] = *(const float4*)&w3[u2*4]; }

  const int ks   = t >> 6;     // wave id = K-slice 0..7
  const int u    = t & 63;
  const int trow = u >> 3;     // rows trow*4..+3
  const int tcol = u & 7;      // cols tcol*4..+3
  const int srow = t >> 4, sh4 = t & 15;   // x staging
  const int whh  = t >> 3, wc4 = t & 7;    // w1 staging
  float acc[4][4] = {};

  for (int h0 = 0; h0 < HID; h0 += 64) {
    __syncthreads();
    {
      const float4 v = *(const float4*)&x[(size_t)(r0+srow)*HID + h0 + sh4*4];
      xT[(sh4*4+0)*36 + srow] = v.x;
      xT[(sh4*4+1)*36 + srow] = v.y;
      xT[(sh4*4+2)*36 + srow] = v.z;
      xT[(sh4*4+3)*36 + srow] = v.w;
      *(float4*)&w1l[whh*36 + wc4*4] = *(const float4*)&w1[(size_t)(h0+whh)*32 + wc4*4];
    }
    __syncthreads();
    #pragma unroll
    for (int s = 0; s < 8; ++s) {
      const int hh = ks*8 + s;
      const float4 xv = *(const float4*)&xT[hh*36 + trow*4];
      const float4 wv = *(const float4*)&w1l[hh*36 + tcol*4];
      const float xa[4] = {xv.x, xv.y, xv.z, xv.w};
      const float wa[4] = {wv.x, wv.y, wv.z, wv.w};
      #pragma unroll
      for (int i = 0; i < 4; ++i)
        #pragma unroll
        for (int j = 0; j < 4; ++j)
          acc[i][j] = fmaf(xa[i], wa[j], acc[i][j]);
    }
  }
  __syncthreads();   // xT/w1l dead; red overlays them
  #pragma unroll
  for (int i = 0; i < 4; ++i) {
    float4 v; v.x = acc[i][0]; v.y = acc[i][1]; v.z = acc[i][2]; v.w = acc[i][3];
    *(float4*)&red[ks*1024 + (trow*4+i)*32 + tcol*4] = v;
  }
  __syncthreads();
  {  // split-K reduce: 2 outputs/thread
    const int i2 = t*2;
    float sx = 0.f, sy = 0.f;
    #pragma unroll
    for (int k = 0; k < 8; ++k) {
      const float2 v = *(const float2*)&red[k*1024 + i2];
      sx += v.x; sy += v.y;
    }
    const int row = i2 >> 5, col = i2 & 31;
    yl[row*33+col]   = sx;
    yl[row*33+col+1] = sy;
  }
  __syncthreads();
  // epilogue: 4 threads/row, 8 dims each
  if (t < 128) {
    const int row = t >> 2, q = t & 3, d0 = q*8;
    float v[8]; float mu = 0.f;
    #pragma unroll
    for (int dd = 0; dd < 8; ++dd) { v[dd] = yl[row*33 + d0+dd] + b1[d0+dd]; mu += v[dd]; }
    mu += __shfl_xor(mu,1); mu += __shfl_xor(mu,2); mu *= (1.f/32.f);
    float var = 0.f;
    #pragma unroll
    for (int dd = 0; dd < 8; ++dd) { const float c = v[dd]-mu; var += c*c; }
    var += __shfl_xor(var,1); var += __shfl_xor(var,2);
    const float rs = rsqrtf(var*(1.f/32.f) + 1e-5f);
    float wiv[16];
    #pragma unroll
    for (int w = 0; w < 16; ++w) wiv[w] = 0.f;
    #pragma unroll
    for (int dd = 0; dd < 8; ++dd) {
      const float hn = (v[dd]-mu)*rs*g1[d0+dd] + beta1[d0+dd];
      const float sl = hn / (1.f + __expf(-hn));
      const float* wr = &w2l[(d0+dd)*16];
      #pragma unroll
      for (int w = 0; w < 16; ++w) wiv[w] = fmaf(sl, wr[w], wiv[w]);
    }
    #pragma unroll
    for (int w = 0; w < 16; ++w) {
      wiv[w] += __shfl_xor(wiv[w],1);
      wiv[w] += __shfl_xor(wiv[w],2);
    }
    float mod[16];
    #pragma unroll
    for (int w = 0; w < 16; ++w) mod[w] = cpl[w]*(1.f + wiv[w] + b2[w]);
    #pragma unroll
    for (int j = 0; j < 4; ++j) msum[row*17 + q*4+j] = mod[q*4+j];
    float p[8];
    #pragma unroll
    for (int dd = 0; dd < 8; ++dd) p[dd] = b3[d0+dd];
    #pragma unroll
    for (int w = 0; w < 16; ++w) {
      const float m = mod[w];
      const float* wr = &w3l[w*32 + d0];
      #pragma unroll
      for (int dd = 0; dd < 8; ++dd) p[dd] = fmaf(m, wr[dd], p[dd]);
    }
    float mu2 = 0.f;
    #pragma unroll
    for (int dd = 0; dd < 8; ++dd) mu2 += p[dd];
    mu2 += __shfl_xor(mu2,1); mu2 += __shfl_xor(mu2,2); mu2 *= (1.f/32.f);
    float var2 = 0.f;
    #pragma unroll
    for (int dd = 0; dd < 8; ++dd) { const float c = p[dd]-mu2; var2 += c*c; }
    var2 += __shfl_xor(var2,1); var2 += __shfl_xor(var2,2);
    const float rs2 = rsqrtf(var2*(1.f/32.f) + 1e-5f);
    float ov[8];
    #pragma unroll
    for (int dd = 0; dd < 8; ++dd) {
      const float hn = (p[dd]-mu2)*rs2*g2[d0+dd] + beta2[d0+dd];
      ov[dd] = hn / (1.f + __expf(-hn));
    }
    float* dst = &o_ws[(size_t)(r0+row)*32 + d0];
    float4 a0; a0.x=ov[0]; a0.y=ov[1]; a0.z=ov[2]; a0.w=ov[3];
    float4 a1; a1.x=ov[4]; a1.y=ov[5]; a1.z=ov[6]; a1.w=ov[7];
    *(float4*)&dst[0] = a0;
    *(float4*)&dst[4] = a1;
  }
  __syncthreads();
  if (t < 16) {
    float s = 0.f;
    for (int r = 0; r < 32; ++r) s += msum[r*17 + t];
    atomicAdd(gacc + t, s);
  }
}

// ---------------------------------------------------------------------------
// Phase 2: resonance_factor -> cpl[16]
// ---------------------------------------------------------------------------
__global__ void wn_phase2(const float* __restrict__ gacc, float* __restrict__ cpl)
{
  __shared__ float res[16];
  const int t = threadIdx.x;
  if (t < 16) {
    const float mw = gacc[t] * (1.f/(float)R_TOTAL);
    res[t] = 0.1f * fabsf(mw);
  }
  __syncthreads();
  if (t == 0) {
    float s = 0.f;
    #pragma unroll
    for (int w = 0; w < 16; ++w) s += res[w];
    cpl[16] = 1.f / (1.f + expf(-s*(1.f/16.f)));
  }
}

// ---------------------------------------------------------------------------
// Phase 3: out = x + rf*(o@w4 + b4).  2048 blocks (256 row-blks x 8 strips),
// 256 thr, 64 rows x 512 cols per block; per-thread 8x4 fp32 tile.
// strip = bid&7 -> each XCD keeps its 64KB w4 slice in L2.
// ---------------------------------------------------------------------------
__global__ __launch_bounds__(256, 6) void wn_phase3(
    const float* __restrict__ x, const float* __restrict__ o_ws,
    const float* __restrict__ w4, const float* __restrict__ b4,
    const float* __restrict__ cpl, float* __restrict__ out)
{
  __shared__ __align__(16) float oT[32*72];     // oT[d][r], stride 72
  __shared__ __align__(16) float w4l[32*128];   // [d][128] linear
  const int t = threadIdx.x;
  const int bid = blockIdx.x;
  const int strip = bid & 7;
  const int r0 = (bid >> 3) * 64;
  const float rf = cpl[16];
  // stage o (row-major read, transpose-scatter into LDS)
  #pragma unroll
  for (int k = 0; k < 2; ++k) {
    const int idx = t + k*256;
    const int r = idx >> 3, c4 = idx & 7;
    const float4 v = *(const float4*)&o_ws[(size_t)(r0+r)*32 + c4*4];
    oT[(c4*4+0)*72 + r] = v.x;
    oT[(c4*4+1)*72 + r] = v.y;
    oT[(c4*4+2)*72 + r] = v.z;
    oT[(c4*4+3)*72 + r] = v.w;
  }
  const int tcol = t & 31;   // cols tcol*4..+3
  const int trow = t >> 5;   // rows trow*8..+7

  for (int c = 0; c < 4; ++c) {
    const int h0 = strip*512 + c*128;
    __syncthreads();
    #pragma unroll
    for (int k = 0; k < 4; ++k) {
      const int idx = t + k*256;
      const int d = idx >> 5, c4 = idx & 31;
      *(float4*)&w4l[d*128 + c4*4] = *(const float4*)&w4[(size_t)d*HID + h0 + c4*4];
    }
    __syncthreads();
    float a[8][4] = {};
    #pragma unroll
    for (int d = 0; d < 32; ++d) {
      const float4 wv = *(const float4*)&w4l[d*128 + tcol*4];
      const float4 o0 = *(const float4*)&oT[d*72 + trow*8];
      const float4 o1 = *(const float4*)&oT[d*72 + trow*8 + 4];
      const float oa[8] = {o0.x,o0.y,o0.z,o0.w,o1.x,o1.y,o1.z,o1.w};
      #pragma unroll
      for (int i = 0; i < 8; ++i) {
        a[i][0] = fmaf(oa[i], wv.x, a[i][0]);
        a[i][1] = fmaf(oa[i], wv.y, a[i][1]);
        a[i][2] = fmaf(oa[i], wv.z, a[i][2]);
        a[i][3] = fmaf(oa[i], wv.w, a[i][3]);
      }
    }
    const float4 bv = *(const float4*)&b4[h0 + tcol*4];
    #pragma unroll
    for (int i = 0; i < 8; ++i) {
      const size_t off = (size_t)(r0 + trow*8 + i)*HID + h0 + tcol*4;
      const float4 xv = *(const float4*)&x[off];
      float4 o2;
      o2.x = fmaf(rf, a[i][0]+bv.x, xv.x);
      o2.y = fmaf(rf, a[i][1]+bv.y, xv.y);
      o2.z = fmaf(rf, a[i][2]+bv.z, xv.z);
      o2.w = fmaf(rf, a[i][3]+bv.w, xv.w);
      *(float4*)&out[off] = o2;
    }
  }
}

extern "C" void kernel_launch(void* const* d_in, const int* in_sizes, int n_in,
                              void* d_out, int out_size, void* d_ws, size_t ws_size,
                              hipStream_t stream) {
  const float* x        = (const float*)d_in[0];
  const float* freq     = (const float*)d_in[1];
  const float* phases   = (const float*)d_in[2];
  const float* coupling = (const float*)d_in[3];
  const float* damping  = (const float*)d_in[4];
  const float* w1       = (const float*)d_in[5];
  const float* b1       = (const float*)d_in[6];
  const float* g1       = (const float*)d_in[7];
  const float* beta1    = (const float*)d_in[8];
  const float* w2       = (const float*)d_in[9];
  const float* b2       = (const float*)d_in[10];
  const float* w3       = (const float*)d_in[11];
  const float* b3       = (const float*)d_in[12];
  const float* g2       = (const float*)d_in[13];
  const float* beta2    = (const float*)d_in[14];
  const float* w4       = (const float*)d_in[15];
  const float* b4       = (const float*)d_in[16];
  const float* tstep    = (const float*)d_in[17];
  float* out = (float*)d_out;

  float* wsf  = (float*)d_ws;
  float* o_ws = wsf;                            // [16384][32]
  float* gacc = wsf + (size_t)R_TOTAL*32;       // [16]
  float* cpl  = gacc + 16;                      // coupled[16] + rf at [16]

  hipMemsetAsync(gacc, 0, 16*sizeof(float), stream);
  hipLaunchKernelGGL(wn_phase0, dim3(1), dim3(64), 0, stream,
                     freq, phases, coupling, damping, tstep, cpl);
  hipLaunchKernelGGL(wn_phase1, dim3(512), dim3(512), 0, stream,
                     x, w1, b1, g1, beta1, w2, b2, w3, b3, g2, beta2, cpl, o_ws, gacc);
  hipLaunchKernelGGL(wn_phase2, dim3(1), dim3(64), 0, stream, gacc, cpl);
  hipLaunchKernelGGL(wn_phase3, dim3(2048), dim3(256), 0, stream,
                     x, o_ws, w4, b4, cpl, out);
}